// Round 11
// baseline (260.342 us; speedup 1.0000x reference)
//
#include <hip/hip_runtime.h>

// B=4, N=8192, CIN=256, H=8, D=64, INNER=512, COUT=256. fp32 I/O.
// out[b] = u_x[b] @ Mb[b] + bo via collapsed per-batch 256x256 matrix.
// All GEMMs: split-bf16 MFMA (x = hi + lo, 3 mfma terms, rel err ~2^-16).
// THIS ROUND: m97 global_load_lds pipeline, spill-free this time.
//  - K-MAJOR fragment-tiled layout: tile (kt, nt) at ((b*8+kt)*ntiles+nt),
//    so a wave's 8 staged tiles per kc are ONE contiguous 8 KiB region
//    (fixes r1's strided-source failure; src = base + lane*16, coalesced).
//  - Rolled kc loop, ONE incremental src pointer per wave (fixes r8's
//    address-materialization spill; persistent cost ~2 VGPR/wave).
//  - Wave-specialized staging: w0=AH w1=AL w2=BH w3=BL; 32 KiB/kc, 64 KiB
//    dbuf; stage buf^1 -> compute buf (ds_read, lgkmcnt) -> barrier
//    (vmcnt drain). Loads fly under same-kc MFMAs = m97 overlap.
//  - Kt/Vt (r9-validated swizzle) alias buf0; norm/dots/prep = r9 verbatim.
// Register model (r2/r5/r6/r7/r8): arch-VGPR cap 128 at (256,2); r9 floor
// 100 -> 28 headroom. Abort signature: VGPR=128 + FETCH>40MB.

#define B_    4
#define N_    8192
#define CIN_  256
#define H_    8
#define D_    64
#define INNER_ 512
#define COUT_ 256
#define EPS_  1e-5f

typedef unsigned short ushort_t;
typedef unsigned int   uint_t;
typedef __attribute__((ext_vector_type(8))) short short8;
typedef __attribute__((ext_vector_type(4))) float f32x4;

__device__ __forceinline__ void split_bf16(float x, ushort_t& hi, ushort_t& lo) {
  const uint_t u = __float_as_uint(x);
  const uint_t hr = (u + 0x8000u) & 0xffff0000u;   // round-half-up to bf16
  hi = (ushort_t)(hr >> 16);
  const float l = x - __uint_as_float(hr);          // exact residual
  lo = (ushort_t)((__float_as_uint(l) + 0x8000u) >> 16);
}

__device__ __forceinline__ void cvt8(float4 x, float4 y, uint4& uh, uint4& ul) {
  const float v[8] = {x.x, x.y, x.z, x.w, y.x, y.y, y.z, y.w};
  ushort_t h[8], l[8];
#pragma unroll
  for (int j = 0; j < 8; j++) split_bf16(v[j], h[j], l[j]);
  uh = make_uint4(h[0] | ((uint_t)h[1] << 16), h[2] | ((uint_t)h[3] << 16),
                  h[4] | ((uint_t)h[5] << 16), h[6] | ((uint_t)h[7] << 16));
  ul = make_uint4(l[0] | ((uint_t)l[1] << 16), l[2] | ((uint_t)l[3] << 16),
                  l[4] | ((uint_t)l[5] << 16), l[6] | ((uint_t)l[7] << 16));
}

#define MFMA(A, Bv, C) __builtin_amdgcn_mfma_f32_16x16x32_bf16((A), (Bv), (C), 0, 0, 0)

// async 16B/lane global->LDS; dst wave-uniform, lane l lands at +16*l.
__device__ __forceinline__ void gl_lds16(const ushort_t* g, char* l) {
  __builtin_amdgcn_global_load_lds(
      (const __attribute__((address_space(1))) void*)(const void*)g,
      (__attribute__((address_space(3))) void*)(void*)l, 16, 0, 0);
}

// K-major fragment tiling: element (row n, col c) of a [rows][256] matrix is
// in tile (kt=c>>5, nt=n>>4), lane = (n&15) | (((c>>3)&3)<<4), elem = c&7.
// Tile = 1 KiB; tile order [kt][nt] (nt contiguous within a kt-plane).

// ---------------------------------------------------------------------------
// Prep: split fp32 -> k-major fragment-tiled bf16 hi/lo. Wave-per-tile:
// contiguous 1 KiB burst per wave per array.
// ---------------------------------------------------------------------------
__global__ __launch_bounds__(256) void prep_ux_kernel(
    const float* __restrict__ u_x, ushort_t* __restrict__ uxH,
    ushort_t* __restrict__ uxL)
{
  const int w = threadIdx.x >> 6, lane = threadIdx.x & 63;
  const uint_t tile = blockIdx.x * 4 + w;       // (b*8+kt)*512 + nt
  const uint_t b = tile >> 12, kt = (tile >> 9) & 7, nt = tile & 511;
  const uint_t r = lane & 15, qv = lane >> 4;
  const size_t src = ((size_t)(b * 8192 + nt * 16 + r)) * 256 + kt * 32 + qv * 8;
  const float4 x = *(const float4*)(u_x + src);
  const float4 y = *(const float4*)(u_x + src + 4);
  uint4 uh, ul;
  cvt8(x, y, uh, ul);
  const size_t dst = (size_t)tile * 512 + (size_t)lane * 8;
  *(uint4*)(uxH + dst) = uh;
  *(uint4*)(uxL + dst) = ul;
}

__global__ __launch_bounds__(256) void prep_w_kernel(
    const float* __restrict__ Wk, const float* __restrict__ Wv,
    ushort_t* __restrict__ WkvH, ushort_t* __restrict__ WkvL)
{
  const uint_t tid = blockIdx.x * 256 + threadIdx.x;  // 0..32767
  const uint_t rr = tid >> 5;            // kv row 0..1023 (K: 0..511, V: 512..)
  const uint_t c0 = (tid & 31) * 8;
  const float* src = (rr < 512) ? (Wk + (size_t)rr * CIN_ + c0)
                                : (Wv + (size_t)(rr - 512) * CIN_ + c0);
  const float4 x = *(const float4*)(src);
  const float4 y = *(const float4*)(src + 4);
  uint4 uh, ul;
  cvt8(x, y, uh, ul);
  const uint_t kt = c0 >> 5, qq = (c0 >> 3) & 3;
  const uint_t lanei = (rr & 15) | (qq << 4);
  // k-major: tile = kt*64 + (rr>>4)
  const size_t dst = (((size_t)kt * 64 + (rr >> 4)) * 64 + lanei) * 8;
  *(uint4*)(WkvH + dst) = uh;
  *(uint4*)(WkvL + dst) = ul;
}

// ---------------------------------------------------------------------------
// Kernel 1: per (chunk of 256 rows, h, b): 2 macro-tiles of 128 rows:
//   KV = u_x @ [Wk_h;Wv_h]^T via gl_lds double-buffered pipeline.
//   InstanceNorm in-register; transpose -> swizzled Kt/Vt (alias buf0);
//   dots += Kt.Vt^T. atomicAdd 64x64 dots per (b,h) at end.
// LDS: 2 x 32 KiB staging (slots: AH 0-7, AL 8-15, BH 16-23 (K then V),
// BL 24-31); Kt/Vt [64][64] r9-swizzle alias buf0. Total 65536 B.
// ---------------------------------------------------------------------------
__global__ __launch_bounds__(256, 2) void kv_dots_kernel(
    const ushort_t* __restrict__ uxH, const ushort_t* __restrict__ uxL,
    const ushort_t* __restrict__ WkvH, const ushort_t* __restrict__ WkvL,
    float* __restrict__ dots)
{
  __shared__ __align__(16) char smem[65536];
  ushort_t* KtH = (ushort_t*)(smem);            // [64][64] swizzled, alias buf0
  ushort_t* KtL = (ushort_t*)(smem + 8192);
  ushort_t* VtH = (ushort_t*)(smem + 16384);
  ushort_t* VtL = (ushort_t*)(smem + 24576);

  const int t = threadIdx.x;
  const int chunk = blockIdx.x, h = blockIdx.y, b = blockIdx.z;
  const int lane = t & 63, wave = t >> 6;
  const int q = lane >> 4, r = lane & 15;
  const int dstripe = 16 * wave;
  const size_t lane8 = (size_t)lane * 8;
  const int laneB = lane * 16;

  // read-slot bases (byte offsets within a 32 KiB buffer)
  const int aSlot = (wave >> 1) * 4;      // AH slots aSlot..+3, AL +8
  const int bSlot = 16 + (wave & 1) * 4;  // BH K/V slots, BL +8

  // per-kc strides (ushorts): A kt-plane = 512 tiles, B kt-plane = 64 tiles
  const size_t kcA = 512 * 512, kcB = 64 * 512;

  f32x4 dacc[4];
#pragma unroll
  for (int j = 0; j < 4; j++) dacc[j] = (f32x4)0.f;

  for (int mt = 0; mt < 2; mt++) {
    const int ntB = chunk * 16 + mt * 8;

    // wave-specialized staging source (kc=0), advanced by kcA/kcB per kc
    const ushort_t* pA = ((wave == 0) ? uxH : uxL) +
                         ((size_t)(b * 8) * 512 + ntB) * 512 + lane8;
    const ushort_t* pKV = ((wave == 2) ? WkvH : WkvL) +
                          (size_t)(h * 4) * 512 + lane8;

    f32x4 acc[4][4];
#pragma unroll
    for (int i = 0; i < 4; i++)
#pragma unroll
      for (int j = 0; j < 4; j++) acc[i][j] = (f32x4)0.f;

    // prologue: stage kc=0 into buf0
    if (wave < 2) {
#pragma unroll
      for (int j = 0; j < 8; j++)
        gl_lds16(pA + j * 512, smem + (wave * 8 + j) * 1024);
    } else {
#pragma unroll
      for (int j = 0; j < 4; j++) {
        gl_lds16(pKV + j * 512, smem + (16 + (wave - 2) * 8 + j) * 1024);
        gl_lds16(pKV + 16384 + j * 512,
                 smem + (16 + (wave - 2) * 8 + 4 + j) * 1024);
      }
    }
    pA += kcA;
    pKV += kcB;
    __syncthreads();

    for (int kc = 0; kc < 8; kc++) {
      if (kc < 7) {
        char* d = smem + (((kc + 1) & 1)) * 32768;
        if (wave < 2) {
#pragma unroll
          for (int j = 0; j < 8; j++)
            gl_lds16(pA + j * 512, d + (wave * 8 + j) * 1024);
        } else {
#pragma unroll
          for (int j = 0; j < 4; j++) {
            gl_lds16(pKV + j * 512, d + (16 + (wave - 2) * 8 + j) * 1024);
            gl_lds16(pKV + 16384 + j * 512,
                     d + (16 + (wave - 2) * 8 + 4 + j) * 1024);
          }
        }
        pA += kcA;
        pKV += kcB;
      }
      const char* sb = smem + (kc & 1) * 32768;
      short8 ahf[4], alf[4];
#pragma unroll
      for (int mi = 0; mi < 4; mi++) {
        ahf[mi] = *(const short8*)(sb + (aSlot + mi) * 1024 + laneB);
        alf[mi] = *(const short8*)(sb + (8 + aSlot + mi) * 1024 + laneB);
      }
#pragma unroll
      for (int nj = 0; nj < 4; nj++) {
        const short8 bhv = *(const short8*)(sb + (bSlot + nj) * 1024 + laneB);
        const short8 blv = *(const short8*)(sb + (8 + bSlot + nj) * 1024 + laneB);
#pragma unroll
        for (int mi = 0; mi < 4; mi++) {
          acc[mi][nj] = MFMA(ahf[mi], bhv, acc[mi][nj]);
          acc[mi][nj] = MFMA(alf[mi], bhv, acc[mi][nj]);
          acc[mi][nj] = MFMA(ahf[mi], blv, acc[mi][nj]);
        }
      }
      __syncthreads();
    }

    // ---- InstanceNorm in-register. Wave's 64 cols are one K/V half; row
    // (seq index) = m0 + 16mi + 4q + reg; stats over 64 cols = sum over nj
    // then over the 16 lanes of the quad.
    float mean[4][4], inv[4][4];
#pragma unroll
    for (int mi = 0; mi < 4; mi++)
#pragma unroll
      for (int reg = 0; reg < 4; reg++) {
        float rs = 0.f, rq = 0.f;
#pragma unroll
        for (int nj = 0; nj < 4; nj++) {
          const float v = acc[mi][nj][reg];
          rs += v;
          rq = fmaf(v, v, rq);
        }
#pragma unroll
        for (int msk = 1; msk < 16; msk <<= 1) {
          rs += __shfl_xor(rs, msk, 64);
          rq += __shfl_xor(rq, msk, 64);
        }
        const float m = rs * (1.f / 64.f);
        const float var = fmaxf(rq * (1.f / 64.f) - m * m, 0.f);
        mean[mi][reg] = m;
        inv[mi][reg] = rsqrtf(var + EPS_);
      }
#pragma unroll
    for (int mi = 0; mi < 4; mi++)
#pragma unroll
      for (int nj = 0; nj < 4; nj++)
#pragma unroll
        for (int reg = 0; reg < 4; reg++)
          acc[mi][nj][reg] = (acc[mi][nj][reg] - mean[mi][reg]) * inv[mi][reg];

    // ---- two 64-row halves: transpose to swizzled LDS, dots MFMA (r9).
    for (int p = 0; p < 2; p++) {
      if ((wave >> 1) == p) {
        ushort_t* Hd = (wave & 1) ? VtH : KtH;
        ushort_t* Ld = (wave & 1) ? VtL : KtL;
#pragma unroll
        for (int nj = 0; nj < 4; nj++) {
          const int d = 16 * nj + r;
#pragma unroll
          for (int mi = 0; mi < 4; mi++) {
            ushort_t hh[4], ll[4];
#pragma unroll
            for (int reg = 0; reg < 4; reg++)
              split_bf16(acc[mi][nj][reg], hh[reg], ll[reg]);
            uint2 ph, pl;
            ph.x = hh[0] | ((uint_t)hh[1] << 16);
            ph.y = hh[2] | ((uint_t)hh[3] << 16);
            pl.x = ll[0] | ((uint_t)ll[1] << 16);
            pl.y = ll[2] | ((uint_t)ll[3] << 16);
            const int bw = ((4 * mi + q) ^ ((d & 7) << 1)) * 4;
            *(uint2*)&Hd[d * 64 + bw] = ph;
            *(uint2*)&Ld[d * 64 + bw] = pl;
          }
        }
      }
      __syncthreads();
#pragma unroll
      for (int ks = 0; ks < 2; ks++) {
        const int ra = dstripe + r;
        const int ca = ((ks * 4 + q) ^ (ra & 7)) * 8;
        const short8 aH = *(const short8*)&KtH[ra * 64 + ca];
        const short8 aL = *(const short8*)&KtL[ra * 64 + ca];
#pragma unroll
        for (int ej = 0; ej < 4; ej++) {
          const int rb = 16 * ej + r;
          const int cb = ((ks * 4 + q) ^ (rb & 7)) * 8;
          const short8 bH = *(const short8*)&VtH[rb * 64 + cb];
          const short8 bL = *(const short8*)&VtL[rb * 64 + cb];
          dacc[ej] = MFMA(aH, bH, dacc[ej]);
          dacc[ej] = MFMA(aL, bH, dacc[ej]);
          dacc[ej] = MFMA(aH, bL, dacc[ej]);
        }
      }
      __syncthreads();
    }
  }

  float* dg = dots + ((size_t)(b * H_ + h)) * 4096;
#pragma unroll
  for (int ej = 0; ej < 4; ej++)
#pragma unroll
    for (int reg = 0; reg < 4; reg++)
      atomicAdd(&dg[(dstripe + 4 * q + reg) * 64 + 16 * ej + r], dacc[ej][reg]);
}

// ---------------------------------------------------------------------------
// Kernel 2a: S[b][hd][o] = sum_e dots[b,h,d,e] * Wo[o, h*64+e]
// ---------------------------------------------------------------------------
__global__ __launch_bounds__(256) void s_kernel(
    const float* __restrict__ dots, const float* __restrict__ Wo,
    float* __restrict__ S)
{
  const int blk = blockIdx.x;  // b*512 + hd
  const int b = blk >> 9, hd = blk & 511, h = hd >> 6;
  __shared__ float drow[64];
  const int t = threadIdx.x;
  if (t < 64) drow[t] = dots[((size_t)(b * H_ + h)) * 4096 + (hd & 63) * 64 + t];
  __syncthreads();
  const float* wp = Wo + (size_t)t * INNER_ + h * 64;
  float acc = 0.f;
#pragma unroll
  for (int e = 0; e < 64; e += 4) {
    const float4 w = *(const float4*)(wp + e);
    acc = fmaf(drow[e + 0], w.x, acc);
    acc = fmaf(drow[e + 1], w.y, acc);
    acc = fmaf(drow[e + 2], w.z, acc);
    acc = fmaf(drow[e + 3], w.w, acc);
  }
  S[((size_t)(b * INNER_) + hd) * COUT_ + t] = acc;
}

// ---------------------------------------------------------------------------
// Kernel 2b: partial Mb over hd-chunks of 128 (grid: 16 c-tiles x 4 b x 4 s)
// ---------------------------------------------------------------------------
__global__ __launch_bounds__(256) void mb_part_kernel(
    const float* __restrict__ Wq, const float* __restrict__ S,
    float* __restrict__ Mbp)
{
  __shared__ __align__(16) float wql[128][16];
  const int c0 = blockIdx.x * 16, b = blockIdx.y, s = blockIdx.z;
  const int t = threadIdx.x;
#pragma unroll
  for (int i = 0; i < 8; i++) {
    const int idx = i * 256 + t;  // 0..2047
    wql[idx >> 4][idx & 15] = Wq[(size_t)(s * 128 + (idx >> 4)) * CIN_ + c0 + (idx & 15)];
  }
  __syncthreads();
  float acc[16];
#pragma unroll
  for (int cp = 0; cp < 16; cp++) acc[cp] = 0.f;
  const float* sp = S + ((size_t)(b * INNER_) + s * 128) * COUT_ + t;
  for (int hd = 0; hd < 128; hd++) {
    const float sv = sp[(size_t)hd * COUT_];
#pragma unroll
    for (int g = 0; g < 4; g++) {
      const float4 w = *(const float4*)&wql[hd][g * 4];
      acc[g * 4 + 0] = fmaf(w.x, sv, acc[g * 4 + 0]);
      acc[g * 4 + 1] = fmaf(w.y, sv, acc[g * 4 + 1]);
      acc[g * 4 + 2] = fmaf(w.z, sv, acc[g * 4 + 2]);
      acc[g * 4 + 3] = fmaf(w.w, sv, acc[g * 4 + 3]);
    }
  }
#pragma unroll
  for (int cp = 0; cp < 16; cp++)
    Mbp[(((size_t)s * 4 + b) * CIN_ + c0 + cp) * COUT_ + t] = acc[cp];
}

// ---------------------------------------------------------------------------
// Kernel 2c: merge 4 partials, scale 1/N, split bf16, write k-major
// fragment-tiled Mbt (tile = (b*8+kt)*16 + ot).
// ---------------------------------------------------------------------------
__global__ __launch_bounds__(256) void mb_merge_kernel(
    const float* __restrict__ Mbp, ushort_t* __restrict__ MbtH,
    ushort_t* __restrict__ MbtL)
{
  const int c0 = blockIdx.x * 16, b = blockIdx.y;
  const int o = threadIdx.x;
#pragma unroll
  for (int cp = 0; cp < 16; cp++) {
    const int c = c0 + cp;
    float v = 0.f;
#pragma unroll
    for (int s = 0; s < 4; s++)
      v += Mbp[(((size_t)s * 4 + b) * CIN_ + c) * COUT_ + o];
    v *= (1.0f / N_);
    ushort_t hi, lo;
    split_bf16(v, hi, lo);
    const uint_t kt = c >> 5, qq = (c >> 3) & 3;
    const uint_t lanei = (o & 15) | (qq << 4);
    const size_t off =
        ((((size_t)(b * 8 + kt)) * 16 + (o >> 4)) * 64 + lanei) * 8 + (c & 7);
    MbtH[off] = hi;
    MbtL[off] = lo;
  }
}

// ---------------------------------------------------------------------------
// Kernel 3: out[b,n,o] = sum_c u_x[b,n,c] * Mbt[o][c] + bo[o], split-bf16
// MFMA, 128x128 tile; gl_lds double-buffered pipeline (same scheme as K1:
// slots AH 0-7, AL 8-15, BH 16-23, BL 24-31). LDS 65536 B.
// ---------------------------------------------------------------------------
__global__ __launch_bounds__(256, 2) void out_kernel(
    const ushort_t* __restrict__ uxH, const ushort_t* __restrict__ uxL,
    const ushort_t* __restrict__ MbtH, const ushort_t* __restrict__ MbtL,
    const float* __restrict__ bo, float* __restrict__ out)
{
  __shared__ __align__(16) char smem[65536];
  const int t = threadIdx.x;
  const int r0 = blockIdx.x * 128, o0 = blockIdx.y * 128, b = blockIdx.z;
  const int lane = t & 63, wave = t >> 6;
  const int q = lane >> 4, r = lane & 15;
  const int m0 = (wave >> 1) * 64, n0 = (wave & 1) * 64;
  const size_t lane8 = (size_t)lane * 8;
  const int laneB = lane * 16;

  const int ntB = r0 >> 4, otB = o0 >> 4;
  const int aSlot = (wave >> 1) * 4;
  const int bSlot = 16 + (wave & 1) * 4;
  const size_t kcA = 512 * 512, kcB = 16 * 512;

  // wave-specialized staging sources (kc=0)
  const ushort_t* pA = ((wave == 0) ? uxH : uxL) +
                       ((size_t)(b * 8) * 512 + ntB) * 512 + lane8;
  const ushort_t* pB = ((wave == 2) ? MbtH : MbtL) +
                       ((size_t)(b * 8) * 16 + otB) * 512 + lane8;

  f32x4 acc[4][4];
#pragma unroll
  for (int i = 0; i < 4; i++)
#pragma unroll
    for (int j = 0; j < 4; j++) acc[i][j] = (f32x4)0.f;

  // prologue: stage kc=0 into buf0
  if (wave < 2) {
#pragma unroll
    for (int j = 0; j < 8; j++)
      gl_lds16(pA + j * 512, smem + (wave * 8 + j) * 1024);
  } else {
#pragma unroll
    for (int j = 0; j < 8; j++)
      gl_lds16(pB + j * 512, smem + (16 + (wave - 2) * 8 + j) * 1024);
  }
  pA += kcA;
  pB += kcB;
  __syncthreads();

  for (int kc = 0; kc < 8; kc++) {
    if (kc < 7) {
      char* d = smem + (((kc + 1) & 1)) * 32768;
      if (wave < 2) {
#pragma unroll
        for (int j = 0; j < 8; j++)
          gl_lds16(pA + j * 512, d + (wave * 8 + j) * 1024);
      } else {
#pragma unroll
        for (int j = 0; j < 8; j++)
          gl_lds16(pB + j * 512, d + (16 + (wave - 2) * 8 + j) * 1024);
      }
      pA += kcA;
      pB += kcB;
    }
    const char* sb = smem + (kc & 1) * 32768;
    short8 ahf[4], alf[4];
#pragma unroll
    for (int mi = 0; mi < 4; mi++) {
      ahf[mi] = *(const short8*)(sb + (aSlot + mi) * 1024 + laneB);
      alf[mi] = *(const short8*)(sb + (8 + aSlot + mi) * 1024 + laneB);
    }
#pragma unroll
    for (int nj = 0; nj < 4; nj++) {
      const short8 bhv = *(const short8*)(sb + (bSlot + nj) * 1024 + laneB);
      const short8 blv = *(const short8*)(sb + (8 + bSlot + nj) * 1024 + laneB);
#pragma unroll
      for (int mi = 0; mi < 4; mi++) {
        acc[mi][nj] = MFMA(ahf[mi], bhv, acc[mi][nj]);
        acc[mi][nj] = MFMA(alf[mi], bhv, acc[mi][nj]);
        acc[mi][nj] = MFMA(ahf[mi], blv, acc[mi][nj]);
      }
    }
    __syncthreads();
  }

  float bov[4];
#pragma unroll
  for (int nj = 0; nj < 4; nj++) bov[nj] = bo[o0 + n0 + 16 * nj + r];
#pragma unroll
  for (int mi = 0; mi < 4; mi++)
#pragma unroll
    for (int nj = 0; nj < 4; nj++) {
      const f32x4 v = acc[mi][nj];
#pragma unroll
      for (int reg = 0; reg < 4; reg++) {
        const int row = r0 + m0 + 16 * mi + q * 4 + reg;
        out[((size_t)(b * N_) + row) * COUT_ + o0 + n0 + 16 * nj + r] =
            v[reg] + bov[nj];
      }
    }
}

extern "C" void kernel_launch(void* const* d_in, const int* in_sizes, int n_in,
                              void* d_out, int out_size, void* d_ws, size_t ws_size,
                              hipStream_t stream) {
  const float* u_x = (const float*)d_in[0];
  // d_in[1] = pos_x (unused)
  const float* Wq = (const float*)d_in[2];
  const float* Wk = (const float*)d_in[3];
  const float* Wv = (const float*)d_in[4];
  const float* Wo = (const float*)d_in[5];
  const float* bo = (const float*)d_in[6];
  float* out = (float*)d_out;

  // ws layout
  ushort_t* uxH  = (ushort_t*)d_ws;        // 8388608
  ushort_t* uxL  = uxH + 8388608;          // 8388608
  ushort_t* WkvH = uxL + 8388608;          // 262144
  ushort_t* WkvL = WkvH + 262144;          // 262144
  ushort_t* MbtH = WkvL + 262144;          // 262144
  ushort_t* MbtL = MbtH + 262144;          // 262144
  float* dots = (float*)(MbtL + 262144);   // 131072 floats
  float* S    = dots + 131072;             // 524288 floats
  float* Mbp  = S + 524288;                // 1048576 floats

  prep_ux_kernel<<<4096, 256, 0, stream>>>(u_x, uxH, uxL);
  prep_w_kernel<<<128, 256, 0, stream>>>(Wk, Wv, WkvH, WkvL);
  hipMemsetAsync(dots, 0, 131072 * sizeof(float), stream);
  kv_dots_kernel<<<dim3(32, 8, 4), 256, 0, stream>>>(uxH, uxL, WkvH, WkvL, dots);
  s_kernel<<<2048, 256, 0, stream>>>(dots, Wo, S);
  mb_part_kernel<<<dim3(16, 4, 4), 256, 0, stream>>>(Wq, S, Mbp);
  mb_merge_kernel<<<dim3(16, 4), 256, 0, stream>>>(Mbp, MbtH, MbtL);
  out_kernel<<<dim3(64, 2, 4), 256, 0, stream>>>(uxH, uxL, MbtH, MbtL, bo, out);
}

// Round 12
// 227.348 us; speedup vs baseline: 1.1451x; 1.1451x over previous
//
#include <hip/hip_runtime.h>

// B=4, N=8192, CIN=256, H=8, D=64, INNER=512, COUT=256. fp32 I/O.
// out[b] = u_x[b] @ Mb[b] + bo via collapsed per-batch 256x256 matrix.
// All GEMMs: split-bf16 MFMA (x = hi + lo, 3 mfma terms, rel err ~2^-16).
// Fragment-tiled global layout: 16x32 MFMA tiles lane-major, 1 KiB each;
// GEMMs read frags directly from global (L2/L3), no staging, no barriers.
// SETTLED (r2/r5/r6/r7/r8/r11 — five spill failures): at (256,2) the
// allocator pins arch-VGPR at 128; r9's loop needs ~100 and ANY structural
// addition (reg prefetch, gl_lds pipeline, extra pointers) spills. The
// GEMM inner loop is frozen at the r9 form.
// THIS ROUND (zero-register): XCD-aware block remap. Grid (32 chunk, 8 h):
// all 8 h-blocks read the SAME 512KB A-panel, but default dispatch strides
// them across 8 XCDs -> 8x redundant L2 fills, A-loads at L3 latency in a
// latency-bound kernel. Bijective remap gives each XCD 4 chunks x 8 heads
// (A working set 2MB <= 4MB L2) -> A-loads become L2 hits. Same idea for
// out_kernel (2 o-blocks per A row-panel co-located).

#define B_    4
#define N_    8192
#define CIN_  256
#define H_    8
#define D_    64
#define INNER_ 512
#define COUT_ 256
#define EPS_  1e-5f

typedef unsigned short ushort_t;
typedef unsigned int   uint_t;
typedef __attribute__((ext_vector_type(8))) short short8;
typedef __attribute__((ext_vector_type(4))) float f32x4;

__device__ __forceinline__ void split_bf16(float x, ushort_t& hi, ushort_t& lo) {
  const uint_t u = __float_as_uint(x);
  const uint_t hr = (u + 0x8000u) & 0xffff0000u;   // round-half-up to bf16
  hi = (ushort_t)(hr >> 16);
  const float l = x - __uint_as_float(hr);          // exact residual
  lo = (ushort_t)((__float_as_uint(l) + 0x8000u) >> 16);
}

__device__ __forceinline__ void cvt8(float4 x, float4 y, uint4& uh, uint4& ul) {
  const float v[8] = {x.x, x.y, x.z, x.w, y.x, y.y, y.z, y.w};
  ushort_t h[8], l[8];
#pragma unroll
  for (int j = 0; j < 8; j++) split_bf16(v[j], h[j], l[j]);
  uh = make_uint4(h[0] | ((uint_t)h[1] << 16), h[2] | ((uint_t)h[3] << 16),
                  h[4] | ((uint_t)h[5] << 16), h[6] | ((uint_t)h[7] << 16));
  ul = make_uint4(l[0] | ((uint_t)l[1] << 16), l[2] | ((uint_t)l[3] << 16),
                  l[4] | ((uint_t)l[5] << 16), l[6] | ((uint_t)l[7] << 16));
}

#define MFMA(A, Bv, C) __builtin_amdgcn_mfma_f32_16x16x32_bf16((A), (Bv), (C), 0, 0, 0)

// Fragment-tiled layout: element (row n, col c) of a [rows][256] matrix lives
// in tile (nt=n>>4, kt=c>>5), lane = (n&15) | (((c>>3)&3)<<4), elem = c&7.
// Tile = 64 lanes x 8 ushorts = 1 KiB, tiles ordered [nt][kt].

// ---------------------------------------------------------------------------
// Prep: split fp32 -> fragment-tiled bf16 hi/lo. Wave-per-tile (r7):
// writes are one contiguous 1 KiB burst per wave per array.
// ---------------------------------------------------------------------------
__global__ __launch_bounds__(256) void prep_ux_kernel(
    const float* __restrict__ u_x, ushort_t* __restrict__ uxH,
    ushort_t* __restrict__ uxL)
{
  const int w = threadIdx.x >> 6, lane = threadIdx.x & 63;
  const uint_t tile = blockIdx.x * 4 + w;       // ((b*512+nt)*8+kt), 0..16383
  const uint_t kt = tile & 7, ntg = tile >> 3;  // ntg = b*512+nt
  const uint_t r = lane & 15, qv = lane >> 4;
  const size_t src = ((size_t)ntg * 16 + r) * 256 + kt * 32 + qv * 8;
  const float4 x = *(const float4*)(u_x + src);
  const float4 y = *(const float4*)(u_x + src + 4);
  uint4 uh, ul;
  cvt8(x, y, uh, ul);
  const size_t dst = (size_t)tile * 512 + (size_t)lane * 8;
  *(uint4*)(uxH + dst) = uh;
  *(uint4*)(uxL + dst) = ul;
}

__global__ __launch_bounds__(256) void prep_w_kernel(
    const float* __restrict__ Wk, const float* __restrict__ Wv,
    ushort_t* __restrict__ WkvH, ushort_t* __restrict__ WkvL)
{
  const uint_t tid = blockIdx.x * 256 + threadIdx.x;  // 0..32767
  const uint_t rr = tid >> 5;            // kv row 0..1023 (K: 0..511, V: 512..)
  const uint_t c0 = (tid & 31) * 8;
  const float* src = (rr < 512) ? (Wk + (size_t)rr * CIN_ + c0)
                                : (Wv + (size_t)(rr - 512) * CIN_ + c0);
  const float4 x = *(const float4*)(src);
  const float4 y = *(const float4*)(src + 4);
  uint4 uh, ul;
  cvt8(x, y, uh, ul);
  const uint_t kt = c0 >> 5, qq = (c0 >> 3) & 3;
  const uint_t lanei = (rr & 15) | (qq << 4);
  const size_t dst = (((size_t)(rr >> 4) * 8 + kt) * 64 + lanei) * 8;
  *(uint4*)(WkvH + dst) = uh;
  *(uint4*)(WkvL + dst) = ul;
}

// ---------------------------------------------------------------------------
// Kernel 1: per (chunk of 256 rows, h, b): 2 macro-tiles of 128 rows:
//   KV = u_x @ [Wk_h;Wv_h]^T : frags direct from tiled global (frozen r9
//   loop). InstanceNorm in-register. Transpose normalized bf16 hi/lo ->
//   swizzled LDS (stride 64 + XOR), dots MFMA.
// XCD remap: flat=(bx+32*by); xcd=flat&7; idx=flat>>3;
//   chunk = xcd*4 + (idx>>3); h = idx&7.  (bijective; A-set 2MB/XCD)
// atomicAdd 64x64 dots per (b,h) at end. LDS: 4x8192 = 32768 B.
// ---------------------------------------------------------------------------
__global__ __launch_bounds__(256, 2) void kv_dots_kernel(
    const ushort_t* __restrict__ uxH, const ushort_t* __restrict__ uxL,
    const ushort_t* __restrict__ WkvH, const ushort_t* __restrict__ WkvL,
    float* __restrict__ dots)
{
  __shared__ __align__(16) char smem[32768];
  ushort_t* KtH = (ushort_t*)(smem);            // [64][64] swizzled
  ushort_t* KtL = (ushort_t*)(smem + 8192);
  ushort_t* VtH = (ushort_t*)(smem + 16384);
  ushort_t* VtL = (ushort_t*)(smem + 24576);

  const int t = threadIdx.x;
  // XCD-aware bijective remap (zero-register lever; dispatch round-robins
  // consecutive flat ids across the 8 XCDs, m09)
  const int flat = blockIdx.x + 32 * blockIdx.y;
  const int xcd = flat & 7, idx = flat >> 3;
  const int chunk = xcd * 4 + (idx >> 3);
  const int h = idx & 7;
  const int b = blockIdx.z;
  const int lane = t & 63, wave = t >> 6;
  const int q = lane >> 4, r = lane & 15;
  const int m0 = (wave >> 1) * 64;
  const int dstripe = 16 * wave;
  const size_t laneoff = (size_t)lane * 8;

  // B tiles (weights) for this wave: K-half rows h*64.. -> tiles h*4+nj;
  // V-half rows 512+h*64.. -> tiles 32+h*4+nj.
  const int rtB0 = ((wave & 1) ? 32 : 0) + h * 4;

  f32x4 dacc[4];
#pragma unroll
  for (int j = 0; j < 4; j++) dacc[j] = (f32x4)0.f;

  for (int mt = 0; mt < 2; mt++) {
    const int nt0 = chunk * 16 + mt * 8 + (m0 >> 4);

    f32x4 acc[4][4];
#pragma unroll
    for (int i = 0; i < 4; i++)
#pragma unroll
      for (int j = 0; j < 4; j++) acc[i][j] = (f32x4)0.f;

    for (int kc = 0; kc < 8; kc++) {
      short8 ahf[4], alf[4];
#pragma unroll
      for (int mi = 0; mi < 4; mi++) {
        const size_t toff =
            (((size_t)b * 512 + nt0 + mi) * 8 + kc) * 512 + laneoff;
        ahf[mi] = *(const short8*)(uxH + toff);
        alf[mi] = *(const short8*)(uxL + toff);
      }
#pragma unroll
      for (int nj = 0; nj < 4; nj++) {
        const size_t boff = ((size_t)(rtB0 + nj) * 8 + kc) * 512 + laneoff;
        const short8 bhv = *(const short8*)(WkvH + boff);
        const short8 blv = *(const short8*)(WkvL + boff);
#pragma unroll
        for (int mi = 0; mi < 4; mi++) {
          acc[mi][nj] = MFMA(ahf[mi], bhv, acc[mi][nj]);
          acc[mi][nj] = MFMA(alf[mi], bhv, acc[mi][nj]);
          acc[mi][nj] = MFMA(ahf[mi], blv, acc[mi][nj]);
        }
      }
    }

    // ---- InstanceNorm in-register. Wave's 64 cols are one K/V half; row
    // (seq index) = m0 + 16mi + 4q + reg; stats over 64 cols = sum over nj
    // then over the 16 lanes of the quad.
    float mean[4][4], inv[4][4];
#pragma unroll
    for (int mi = 0; mi < 4; mi++)
#pragma unroll
      for (int reg = 0; reg < 4; reg++) {
        float rs = 0.f, rq = 0.f;
#pragma unroll
        for (int nj = 0; nj < 4; nj++) {
          const float v = acc[mi][nj][reg];
          rs += v;
          rq = fmaf(v, v, rq);
        }
#pragma unroll
        for (int msk = 1; msk < 16; msk <<= 1) {
          rs += __shfl_xor(rs, msk, 64);
          rq += __shfl_xor(rq, msk, 64);
        }
        const float m = rs * (1.f / 64.f);
        const float var = fmaxf(rq * (1.f / 64.f) - m * m, 0.f);
        mean[mi][reg] = m;
        inv[mi][reg] = rsqrtf(var + EPS_);
      }
#pragma unroll
    for (int mi = 0; mi < 4; mi++)
#pragma unroll
      for (int nj = 0; nj < 4; nj++)
#pragma unroll
        for (int reg = 0; reg < 4; reg++)
          acc[mi][nj][reg] = (acc[mi][nj][reg] - mean[mi][reg]) * inv[mi][reg];

    // ---- two 64-row halves: transpose to swizzled LDS, dots MFMA (r9).
    // Row = feature d (0..63), 64 ushorts/row; 8B write block at
    // (4*mi+q) ^ ((d&7)<<1); 16B read block at (ks*4+q) ^ (d&7).
    for (int p = 0; p < 2; p++) {
      if ((wave >> 1) == p) {
        ushort_t* Hd = (wave & 1) ? VtH : KtH;
        ushort_t* Ld = (wave & 1) ? VtL : KtL;
#pragma unroll
        for (int nj = 0; nj < 4; nj++) {
          const int d = 16 * nj + r;
#pragma unroll
          for (int mi = 0; mi < 4; mi++) {
            ushort_t hh[4], ll[4];
#pragma unroll
            for (int reg = 0; reg < 4; reg++)
              split_bf16(acc[mi][nj][reg], hh[reg], ll[reg]);
            uint2 ph, pl;
            ph.x = hh[0] | ((uint_t)hh[1] << 16);
            ph.y = hh[2] | ((uint_t)hh[3] << 16);
            pl.x = ll[0] | ((uint_t)ll[1] << 16);
            pl.y = ll[2] | ((uint_t)ll[3] << 16);
            const int bw = ((4 * mi + q) ^ ((d & 7) << 1)) * 4;
            *(uint2*)&Hd[d * 64 + bw] = ph;
            *(uint2*)&Ld[d * 64 + bw] = pl;
          }
        }
      }
      __syncthreads();
#pragma unroll
      for (int ks = 0; ks < 2; ks++) {
        const int ra = dstripe + r;
        const int ca = ((ks * 4 + q) ^ (ra & 7)) * 8;
        const short8 aH = *(const short8*)&KtH[ra * 64 + ca];
        const short8 aL = *(const short8*)&KtL[ra * 64 + ca];
#pragma unroll
        for (int ej = 0; ej < 4; ej++) {
          const int rb = 16 * ej + r;
          const int cb = ((ks * 4 + q) ^ (rb & 7)) * 8;
          const short8 bH = *(const short8*)&VtH[rb * 64 + cb];
          const short8 bL = *(const short8*)&VtL[rb * 64 + cb];
          dacc[ej] = MFMA(aH, bH, dacc[ej]);
          dacc[ej] = MFMA(aL, bH, dacc[ej]);
          dacc[ej] = MFMA(aH, bL, dacc[ej]);
        }
      }
      __syncthreads();
    }
  }

  float* dg = dots + ((size_t)(b * H_ + h)) * 4096;
#pragma unroll
  for (int ej = 0; ej < 4; ej++)
#pragma unroll
    for (int reg = 0; reg < 4; reg++)
      atomicAdd(&dg[(dstripe + 4 * q + reg) * 64 + 16 * ej + r], dacc[ej][reg]);
}

// ---------------------------------------------------------------------------
// Kernel 2a: S[b][hd][o] = sum_e dots[b,h,d,e] * Wo[o, h*64+e]
// ---------------------------------------------------------------------------
__global__ __launch_bounds__(256) void s_kernel(
    const float* __restrict__ dots, const float* __restrict__ Wo,
    float* __restrict__ S)
{
  const int blk = blockIdx.x;  // b*512 + hd
  const int b = blk >> 9, hd = blk & 511, h = hd >> 6;
  __shared__ float drow[64];
  const int t = threadIdx.x;
  if (t < 64) drow[t] = dots[((size_t)(b * H_ + h)) * 4096 + (hd & 63) * 64 + t];
  __syncthreads();
  const float* wp = Wo + (size_t)t * INNER_ + h * 64;
  float acc = 0.f;
#pragma unroll
  for (int e = 0; e < 64; e += 4) {
    const float4 w = *(const float4*)(wp + e);
    acc = fmaf(drow[e + 0], w.x, acc);
    acc = fmaf(drow[e + 1], w.y, acc);
    acc = fmaf(drow[e + 2], w.z, acc);
    acc = fmaf(drow[e + 3], w.w, acc);
  }
  S[((size_t)(b * INNER_) + hd) * COUT_ + t] = acc;
}

// ---------------------------------------------------------------------------
// Kernel 2b: partial Mb over hd-chunks of 128 (grid: 16 c-tiles x 4 b x 4 s)
// ---------------------------------------------------------------------------
__global__ __launch_bounds__(256) void mb_part_kernel(
    const float* __restrict__ Wq, const float* __restrict__ S,
    float* __restrict__ Mbp)
{
  __shared__ __align__(16) float wql[128][16];
  const int c0 = blockIdx.x * 16, b = blockIdx.y, s = blockIdx.z;
  const int t = threadIdx.x;
#pragma unroll
  for (int i = 0; i < 8; i++) {
    const int idx = i * 256 + t;  // 0..2047
    wql[idx >> 4][idx & 15] = Wq[(size_t)(s * 128 + (idx >> 4)) * CIN_ + c0 + (idx & 15)];
  }
  __syncthreads();
  float acc[16];
#pragma unroll
  for (int cp = 0; cp < 16; cp++) acc[cp] = 0.f;
  const float* sp = S + ((size_t)(b * INNER_) + s * 128) * COUT_ + t;
  for (int hd = 0; hd < 128; hd++) {
    const float sv = sp[(size_t)hd * COUT_];
#pragma unroll
    for (int g = 0; g < 4; g++) {
      const float4 w = *(const float4*)&wql[hd][g * 4];
      acc[g * 4 + 0] = fmaf(w.x, sv, acc[g * 4 + 0]);
      acc[g * 4 + 1] = fmaf(w.y, sv, acc[g * 4 + 1]);
      acc[g * 4 + 2] = fmaf(w.z, sv, acc[g * 4 + 2]);
      acc[g * 4 + 3] = fmaf(w.w, sv, acc[g * 4 + 3]);
    }
  }
#pragma unroll
  for (int cp = 0; cp < 16; cp++)
    Mbp[(((size_t)s * 4 + b) * CIN_ + c0 + cp) * COUT_ + t] = acc[cp];
}

// ---------------------------------------------------------------------------
// Kernel 2c: merge 4 partials, scale 1/N, split bf16, write fragment-tiled
// Mbt (o-row-tiled over CIN, same tiling as uxH).
// ---------------------------------------------------------------------------
__global__ __launch_bounds__(256) void mb_merge_kernel(
    const float* __restrict__ Mbp, ushort_t* __restrict__ MbtH,
    ushort_t* __restrict__ MbtL)
{
  const int c0 = blockIdx.x * 16, b = blockIdx.y;
  const int o = threadIdx.x;
#pragma unroll
  for (int cp = 0; cp < 16; cp++) {
    const int c = c0 + cp;
    float v = 0.f;
#pragma unroll
    for (int s = 0; s < 4; s++)
      v += Mbp[(((size_t)s * 4 + b) * CIN_ + c) * COUT_ + o];
    v *= (1.0f / N_);
    ushort_t hi, lo;
    split_bf16(v, hi, lo);
    const uint_t kt = c >> 5, qq = (c >> 3) & 3;
    const uint_t lanei = (o & 15) | (qq << 4);
    const size_t off =
        ((((size_t)b * 16 + (o >> 4)) * 8 + kt) * 64 + lanei) * 8 + (c & 7);
    MbtH[off] = hi;
    MbtL[off] = lo;
  }
}

// ---------------------------------------------------------------------------
// Kernel 3: out[b,n,o] = sum_c u_x[b,n,c] * Mbt[o][c] + bo[o], split-bf16
// MFMA, 128x128 tile; frags direct from tiled global (frozen r9 loop).
// XCD remap: flat=(bx+2*...); co-locate the 2 o-blocks per A row-panel.
// No LDS, no barriers.
// ---------------------------------------------------------------------------
__global__ __launch_bounds__(256, 2) void out_kernel(
    const ushort_t* __restrict__ uxH, const ushort_t* __restrict__ uxL,
    const ushort_t* __restrict__ MbtH, const ushort_t* __restrict__ MbtL,
    const float* __restrict__ bo, float* __restrict__ out)
{
  const int t = threadIdx.x;
  // XCD-aware remap: flat 0..127; xcd=flat&7; idx=flat>>3 (0..15);
  // row-panel = xcd*8 + (idx>>1), o-half = idx&1  (bijective)
  const int flat = blockIdx.x + 64 * blockIdx.y;
  const int xcd = flat & 7, idx = flat >> 3;
  const int r0 = (xcd * 8 + (idx >> 1)) * 128;
  const int o0 = (idx & 1) * 128;
  const int b = blockIdx.z;
  const int lane = t & 63, wave = t >> 6;
  const int q = lane >> 4, r = lane & 15;
  const int m0 = (wave >> 1) * 64, n0 = (wave & 1) * 64;
  const size_t laneoff = (size_t)lane * 8;

  const int nt0 = (r0 + m0) >> 4;
  const int ot0 = (o0 + n0) >> 4;

  f32x4 acc[4][4];
#pragma unroll
  for (int i = 0; i < 4; i++)
#pragma unroll
    for (int j = 0; j < 4; j++) acc[i][j] = (f32x4)0.f;

  for (int kc = 0; kc < 8; kc++) {
    short8 ahf[4], alf[4];
#pragma unroll
    for (int mi = 0; mi < 4; mi++) {
      const size_t toff =
          (((size_t)b * 512 + nt0 + mi) * 8 + kc) * 512 + laneoff;
      ahf[mi] = *(const short8*)(uxH + toff);
      alf[mi] = *(const short8*)(uxL + toff);
    }
#pragma unroll
    for (int nj = 0; nj < 4; nj++) {
      const size_t boff =
          (((size_t)b * 16 + ot0 + nj) * 8 + kc) * 512 + laneoff;
      const short8 bhv = *(const short8*)(MbtH + boff);
      const short8 blv = *(const short8*)(MbtL + boff);
#pragma unroll
      for (int mi = 0; mi < 4; mi++) {
        acc[mi][nj] = MFMA(ahf[mi], bhv, acc[mi][nj]);
        acc[mi][nj] = MFMA(alf[mi], bhv, acc[mi][nj]);
        acc[mi][nj] = MFMA(ahf[mi], blv, acc[mi][nj]);
      }
    }
  }

  float bov[4];
#pragma unroll
  for (int nj = 0; nj < 4; nj++) bov[nj] = bo[o0 + n0 + 16 * nj + r];
#pragma unroll
  for (int mi = 0; mi < 4; mi++)
#pragma unroll
    for (int nj = 0; nj < 4; nj++) {
      const f32x4 v = acc[mi][nj];
#pragma unroll
      for (int reg = 0; reg < 4; reg++) {
        const int row = r0 + m0 + 16 * mi + q * 4 + reg;
        out[((size_t)(b * N_) + row) * COUT_ + o0 + n0 + 16 * nj + r] =
            v[reg] + bov[nj];
      }
    }
}

extern "C" void kernel_launch(void* const* d_in, const int* in_sizes, int n_in,
                              void* d_out, int out_size, void* d_ws, size_t ws_size,
                              hipStream_t stream) {
  const float* u_x = (const float*)d_in[0];
  // d_in[1] = pos_x (unused)
  const float* Wq = (const float*)d_in[2];
  const float* Wk = (const float*)d_in[3];
  const float* Wv = (const float*)d_in[4];
  const float* Wo = (const float*)d_in[5];
  const float* bo = (const float*)d_in[6];
  float* out = (float*)d_out;

  // ws layout
  ushort_t* uxH  = (ushort_t*)d_ws;        // 8388608
  ushort_t* uxL  = uxH + 8388608;          // 8388608
  ushort_t* WkvH = uxL + 8388608;          // 262144
  ushort_t* WkvL = WkvH + 262144;          // 262144
  ushort_t* MbtH = WkvL + 262144;          // 262144
  ushort_t* MbtL = MbtH + 262144;          // 262144
  float* dots = (float*)(MbtL + 262144);   // 131072 floats
  float* S    = dots + 131072;             // 524288 floats
  float* Mbp  = S + 524288;                // 1048576 floats

  prep_ux_kernel<<<4096, 256, 0, stream>>>(u_x, uxH, uxL);
  prep_w_kernel<<<128, 256, 0, stream>>>(Wk, Wv, WkvH, WkvL);
  hipMemsetAsync(dots, 0, 131072 * sizeof(float), stream);
  kv_dots_kernel<<<dim3(32, 8, 4), 256, 0, stream>>>(uxH, uxL, WkvH, WkvL, dots);
  s_kernel<<<2048, 256, 0, stream>>>(dots, Wo, S);
  mb_part_kernel<<<dim3(16, 4, 4), 256, 0, stream>>>(Wq, S, Mbp);
  mb_merge_kernel<<<dim3(16, 4), 256, 0, stream>>>(Mbp, MbtH, MbtL);
  out_kernel<<<dim3(64, 2, 4), 256, 0, stream>>>(uxH, uxL, MbtH, MbtL, bo, out);
}